// Round 6
// baseline (435.006 us; speedup 1.0000x reference)
//
#include <hip/hip_runtime.h>
#include <hip/hip_bf16.h>

#define NNODES 100000
#define NEDGES 1600000
#define KDIM 256
#define ODIM 128
#define NB_SCAN 98        // ceil(100000 / 1024)
#define EDGE_CAP 1900032  // 1.6M + 3*100000, rounded up a bit
#define ESTRIDE 400000    // NEDGES / 4
#define GEMM_BLOCKS 1563  // ceil(100000 / 64)
#define RANK_BLOCKS 1563  // ceil(400000 / 256)

typedef __attribute__((ext_vector_type(8))) short short8;
typedef __attribute__((ext_vector_type(4))) float floatx4;

// round-to-nearest-even f32 -> bf16 (inputs are finite Gaussians; no NaN handling needed)
static __device__ __forceinline__ short f2bf(float f) {
  union { float f; unsigned u; } x; x.f = f;
  unsigned r = (x.u + 0x7fffu + ((x.u >> 16) & 1u)) >> 16;
  return (short)r;
}

__global__ void conv_w_kernel(const float* __restrict__ W, short* __restrict__ Wb) {
  int i = blockIdx.x * 256 + threadIdx.x;
  if (i < ODIM * KDIM) Wb[i] = f2bf(W[i]);
}

// per-1024-chunk exclusive scan of PADDED counts ((c+3)&~3) + chunk totals
__global__ void scan1_kernel(const int* __restrict__ counts, int* __restrict__ chunkExcl,
                             int* __restrict__ blockSums) {
  __shared__ int s[256];
  int t = threadIdx.x;
  int base = blockIdx.x * 1024 + t * 4;
  int v[4];
#pragma unroll
  for (int j = 0; j < 4; j++) {
    int idx = base + j;
    v[j] = (idx < NNODES) ? ((counts[idx] + 3) & ~3) : 0;  // pad to multiple of 4
  }
  int sum = v[0] + v[1] + v[2] + v[3];
  s[t] = sum;
  __syncthreads();
  for (int o = 1; o < 256; o <<= 1) {
    int add = (t >= o) ? s[t - o] : 0;
    __syncthreads();
    s[t] += add;
    __syncthreads();
  }
  int run = s[t] - sum;
#pragma unroll
  for (int j = 0; j < 4; j++) {
    int idx = base + j;
    if (idx < NNODES) chunkExcl[idx] = run;
    run += v[j];
  }
  if (t == 255) blockSums[blockIdx.x] = s[255];
}

// single-block exclusive scan of the 98 chunk totals; also writes offsets[NNODES] = total
__global__ void scan2_kernel(const int* __restrict__ blockSums, int* __restrict__ blockBase,
                             int* __restrict__ offsets) {
  __shared__ int s[128];
  int t = threadIdx.x;
  int v = (t < NB_SCAN) ? blockSums[t] : 0;
  s[t] = v;
  __syncthreads();
  for (int o = 1; o < 128; o <<= 1) {
    int add = (t >= o) ? s[t - o] : 0;
    __syncthreads();
    s[t] += add;
    __syncthreads();
  }
  if (t < NB_SCAN) blockBase[t] = s[t] - v;
  if (t == 127) offsets[NNODES] = s[127];
}

__global__ void scan3_kernel(const int* __restrict__ chunkExcl, const int* __restrict__ blockBase,
                             int* __restrict__ offsets) {
  int i = blockIdx.x * 256 + threadIdx.x;
  if (i < NNODES) offsets[i] = chunkExcl[i] + blockBase[i >> 10];
}

// Atomic-free placement: pos = offsets[row] + rank. offsets is 400 KB (L2-resident
// random read); the scattered 8 B store has no RMW dependency -> pipelines freely.
__global__ void place_kernel(const int* __restrict__ rows, const int* __restrict__ cols,
                             const float* __restrict__ vals,
                             const unsigned short* __restrict__ rank,
                             const int* __restrict__ offsets, int2* __restrict__ edges) {
  int i = blockIdx.x * 256 + threadIdx.x;
#pragma unroll
  for (int j = 0; j < 4; j++) {
    int e = i + j * ESTRIDE;
    if (e < NEDGES) {
      int r = rows[e];
      int p = offsets[r] + (int)rank[e];
      int2 rec;
      rec.x = cols[e];
      rec.y = __float_as_int(vals[e]);
      edges[p] = rec;
    }
  }
}

// Fused: blocks [0, GEMM_BLOCKS) compute H = bf16(X @ W^T + b); blocks
// [GEMM_BLOCKS, +RANK_BLOCKS) run histogram+rank atomics (independent work,
// hides under the gemm's HBM streaming).
//
// gemm: 64 rows/block, 16 rows/wave, all 8 n-tiles per wave. ALL 16 X-float4
// loads are pulled into a register array BEFORE the K-loop: ~16 KB/wave of HBM
// traffic in flight (the VGPR=64 build of R4 had ~2 loads in flight -> pure
// latency stall at 1.1 TB/s). VGPR ~160 / 3 waves/SIMD is the right trade:
// 12 waves/CU x 16 KB >> the ~9 KB/CU needed to saturate HBM.
// D: col = lane&15, row = quad*4 + reg  [m89 layout]
__global__ __launch_bounds__(256) void gemm_rank_kernel(
    const float* __restrict__ X, const short* __restrict__ Wb,
    const float* __restrict__ bias, unsigned short* __restrict__ H,
    const int* __restrict__ rows, int* __restrict__ counts,
    unsigned short* __restrict__ rank) {
  if (blockIdx.x >= GEMM_BLOCKS) {
    // ---- rank path: 4 independent atomic chains per thread ----
    int i = (blockIdx.x - GEMM_BLOCKS) * 256 + threadIdx.x;
#pragma unroll
    for (int j = 0; j < 4; j++) {
      int e = i + j * ESTRIDE;
      if (e < NEDGES) {
        int r = rows[e];
        rank[e] = (unsigned short)atomicAdd(&counts[r], 1);
      }
    }
    return;
  }
  // ---- gemm path ----
  const int lane = threadIdx.x & 63;
  const int wave = threadIdx.x >> 6;
  const int l16 = lane & 15;
  const int quad = lane >> 4;
  const int rowBase = blockIdx.x * 64 + wave * 16;
  const int arow = rowBase + l16;
  const bool inb = arow < NNODES;
  const float4 zf4 = {0.f, 0.f, 0.f, 0.f};
  const float4* xp = (const float4*)(X + (size_t)(inb ? arow : 0) * KDIM);

  // Hoist the lane's entire X row-slice: 16 float4 loads issued back-to-back
  float4 xv[16];
#pragma unroll
  for (int k0 = 0; k0 < 8; k0++) {
    xv[2 * k0] = inb ? xp[quad * 2 + k0 * 8] : zf4;
    xv[2 * k0 + 1] = inb ? xp[quad * 2 + k0 * 8 + 1] : zf4;
  }

  floatx4 acc[8];
#pragma unroll
  for (int t = 0; t < 8; t++) acc[t] = (floatx4){0.f, 0.f, 0.f, 0.f};

#pragma unroll
  for (int k0 = 0; k0 < 8; k0++) {
    const float4 c0 = xv[2 * k0];
    const float4 c1 = xv[2 * k0 + 1];
    short8 a;
    a[0] = f2bf(c0.x); a[1] = f2bf(c0.y); a[2] = f2bf(c0.z); a[3] = f2bf(c0.w);
    a[4] = f2bf(c1.x); a[5] = f2bf(c1.y); a[6] = f2bf(c1.z); a[7] = f2bf(c1.w);
    const short* bp = Wb + k0 * 32 + quad * 8;
#pragma unroll
    for (int t = 0; t < 8; t++) {
      short8 b = *(const short8*)(bp + (size_t)(t * 16 + l16) * KDIM);
      acc[t] = __builtin_amdgcn_mfma_f32_16x16x32_bf16(a, b, acc[t], 0, 0, 0);
    }
  }

#pragma unroll
  for (int t = 0; t < 8; t++) {
    const int col = t * 16 + l16;
    const float bv = bias[col];
#pragma unroll
    for (int r = 0; r < 4; r++) {
      const int row = rowBase + quad * 4 + r;
      if (row < NNODES) H[(size_t)row * ODIM + col] = (unsigned short)f2bf(acc[t][r] + bv);
    }
  }
}

// Two rows per wave = 2 independent gather chains (8 gathers in flight), CSR with
// 4-padded segments (pad records are {col 0, val 0} from the memset -> no masking;
// the i<len guards are wave-uniform branches, both rows belong to the whole wave).
// Lane owns channels {2*lane, 2*lane+1}: one uint = 2 bf16, 256 B/edge coalesced.
__global__ __launch_bounds__(256) void spmm_kernel(const int* __restrict__ offsets,
                                                   const int2* __restrict__ edges,
                                                   const unsigned* __restrict__ H2,
                                                   float* __restrict__ out) {
  const int lane = threadIdx.x & 63;
  const int wid = blockIdx.x * 4 + (threadIdx.x >> 6);
  const int r0 = wid * 2;
  const int r1 = r0 + 1;  // NNODES even -> r1 valid whenever r0 is
  if (r0 >= NNODES) return;
  const int s0 = offsets[r0];
  const int s1 = offsets[r1];
  const int e1 = offsets[r1 + 1];
  const int len0 = s1 - s0;  // padded, multiple of 4
  const int len1 = e1 - s1;
  const int2* p0 = edges + s0;
  const int2* p1 = edges + s1;
  float ax0 = 0.f, ay0 = 0.f, ax1 = 0.f, ay1 = 0.f;
  const int it = len0 > len1 ? len0 : len1;
#define EDGE_ACC(px, py, ax, ay)                              \
  {                                                           \
    const unsigned h = H2[(size_t)(px) * 64 + lane];          \
    const float v = __int_as_float(py);                       \
    ax += v * __uint_as_float(h << 16);                       \
    ay += v * __uint_as_float(h & 0xffff0000u);               \
  }
  for (int i = 0; i < it; i += 4) {
    if (i < len0) {
      const int4 a01 = *(const int4*)(p0 + i);
      const int4 a23 = *(const int4*)(p0 + i + 2);
      EDGE_ACC(a01.x, a01.y, ax0, ay0)
      EDGE_ACC(a01.z, a01.w, ax0, ay0)
      EDGE_ACC(a23.x, a23.y, ax0, ay0)
      EDGE_ACC(a23.z, a23.w, ax0, ay0)
    }
    if (i < len1) {
      const int4 b01 = *(const int4*)(p1 + i);
      const int4 b23 = *(const int4*)(p1 + i + 2);
      EDGE_ACC(b01.x, b01.y, ax1, ay1)
      EDGE_ACC(b01.z, b01.w, ax1, ay1)
      EDGE_ACC(b23.x, b23.y, ax1, ay1)
      EDGE_ACC(b23.z, b23.w, ax1, ay1)
    }
  }
#undef EDGE_ACC
  float2 o0, o1;
  o0.x = ax0; o0.y = ay0;
  o1.x = ax1; o1.y = ay1;
  ((float2*)out)[(size_t)r0 * 64 + lane] = o0;
  ((float2*)out)[(size_t)r1 * 64 + lane] = o1;
}

extern "C" void kernel_launch(void* const* d_in, const int* in_sizes, int n_in,
                              void* d_out, int out_size, void* d_ws, size_t ws_size,
                              hipStream_t stream) {
  const float* X = (const float*)d_in[0];
  const int* erow = (const int*)d_in[1];
  const int* ecol = (const int*)d_in[2];
  const float* eval = (const float*)d_in[3];
  const float* W = (const float*)d_in[4];
  const float* bias = (const float*)d_in[5];
  float* out = (float*)d_out;

  char* ws = (char*)d_ws;
  size_t off = 0;
  auto alloc = [&](size_t bytes) -> char* {
    char* p = ws + off;
    off += (bytes + 255) & ~(size_t)255;
    return p;
  };
  // total ~45.4 MB — matches the R4 footprint that is known to fit ws_size
  unsigned short* Hb = (unsigned short*)alloc((size_t)NNODES * ODIM * 2);  // 25.6 MB
  short* Wb = (short*)alloc((size_t)ODIM * KDIM * 2);                      // 64 KB
  int* counts = (int*)alloc((size_t)NNODES * 4);
  int* chunkExcl = (int*)alloc((size_t)NNODES * 4);
  int* offsets = (int*)alloc((size_t)(NNODES + 1) * 4);
  int* blockSums = (int*)alloc((size_t)NB_SCAN * 4);
  int* blockBase = (int*)alloc((size_t)NB_SCAN * 4);
  unsigned short* rank = (unsigned short*)alloc((size_t)NEDGES * 2);  // 3.2 MB
  int2* edges = (int2*)alloc((size_t)EDGE_CAP * 8);  // 15.2 MB, padded CSR records

  hipMemsetAsync(counts, 0, (size_t)NNODES * 4, stream);
  hipMemsetAsync(edges, 0, (size_t)EDGE_CAP * 8, stream);  // pad records = {col 0, val 0}
  conv_w_kernel<<<(ODIM * KDIM + 255) / 256, 256, 0, stream>>>(W, Wb);
  gemm_rank_kernel<<<GEMM_BLOCKS + RANK_BLOCKS, 256, 0, stream>>>(X, Wb, bias, Hb,
                                                                 erow, counts, rank);
  scan1_kernel<<<NB_SCAN, 256, 0, stream>>>(counts, chunkExcl, blockSums);
  scan2_kernel<<<1, 128, 0, stream>>>(blockSums, blockBase, offsets);
  scan3_kernel<<<(NNODES + 255) / 256, 256, 0, stream>>>(chunkExcl, blockBase, offsets);
  place_kernel<<<(ESTRIDE + 255) / 256, 256, 0, stream>>>(erow, ecol, eval, rank, offsets, edges);
  spmm_kernel<<<(NNODES / 2 + 3) / 4, 256, 0, stream>>>(offsets, edges, (const unsigned*)Hb, out);
}

// Round 7
// 425.623 us; speedup vs baseline: 1.0220x; 1.0220x over previous
//
#include <hip/hip_runtime.h>
#include <hip/hip_bf16.h>

#define NNODES 100000
#define NEDGES 1600000
#define KDIM 256
#define ODIM 128
#define NB_SCAN 98        // ceil(100000 / 1024)
#define EDGE_CAP 1900032  // 1.6M + 3*100000, rounded up a bit
#define ESTRIDE 400000    // NEDGES / 4
#define GEMM_BLOCKS 1563  // ceil(100000 / 64)
#define RANK_BLOCKS 782   // ceil(400000 / 512)

typedef __attribute__((ext_vector_type(8))) short short8;
typedef __attribute__((ext_vector_type(4))) float floatx4;
typedef const __attribute__((address_space(1))) unsigned gas_u32;
typedef __attribute__((address_space(3))) unsigned lds_u32;

// round-to-nearest-even f32 -> bf16 (inputs are finite Gaussians; no NaN handling needed)
static __device__ __forceinline__ short f2bf(float f) {
  union { float f; unsigned u; } x; x.f = f;
  unsigned r = (x.u + 0x7fffu + ((x.u >> 16) & 1u)) >> 16;
  return (short)r;
}

__global__ void conv_w_kernel(const float* __restrict__ W, short* __restrict__ Wb) {
  int i = blockIdx.x * 256 + threadIdx.x;
  if (i < ODIM * KDIM) Wb[i] = f2bf(W[i]);
}

// per-1024-chunk exclusive scan of PADDED counts ((c+3)&~3) + chunk totals
__global__ void scan1_kernel(const int* __restrict__ counts, int* __restrict__ chunkExcl,
                             int* __restrict__ blockSums) {
  __shared__ int s[256];
  int t = threadIdx.x;
  int base = blockIdx.x * 1024 + t * 4;
  int v[4];
#pragma unroll
  for (int j = 0; j < 4; j++) {
    int idx = base + j;
    v[j] = (idx < NNODES) ? ((counts[idx] + 3) & ~3) : 0;  // pad to multiple of 4
  }
  int sum = v[0] + v[1] + v[2] + v[3];
  s[t] = sum;
  __syncthreads();
  for (int o = 1; o < 256; o <<= 1) {
    int add = (t >= o) ? s[t - o] : 0;
    __syncthreads();
    s[t] += add;
    __syncthreads();
  }
  int run = s[t] - sum;
#pragma unroll
  for (int j = 0; j < 4; j++) {
    int idx = base + j;
    if (idx < NNODES) chunkExcl[idx] = run;
    run += v[j];
  }
  if (t == 255) blockSums[blockIdx.x] = s[255];
}

// single-block exclusive scan of the 98 chunk totals; also writes offsets[NNODES] = total
__global__ void scan2_kernel(const int* __restrict__ blockSums, int* __restrict__ blockBase,
                             int* __restrict__ offsets) {
  __shared__ int s[128];
  int t = threadIdx.x;
  int v = (t < NB_SCAN) ? blockSums[t] : 0;
  s[t] = v;
  __syncthreads();
  for (int o = 1; o < 128; o <<= 1) {
    int add = (t >= o) ? s[t - o] : 0;
    __syncthreads();
    s[t] += add;
    __syncthreads();
  }
  if (t < NB_SCAN) blockBase[t] = s[t] - v;
  if (t == 127) offsets[NNODES] = s[127];
}

__global__ void scan3_kernel(const int* __restrict__ chunkExcl, const int* __restrict__ blockBase,
                             int* __restrict__ offsets) {
  int i = blockIdx.x * 256 + threadIdx.x;
  if (i < NNODES) offsets[i] = chunkExcl[i] + blockBase[i >> 10];
}

// Atomic-free placement: pos = offsets[row] + rank. offsets is 400 KB (L2-resident
// random read); the scattered 8 B store has no RMW dependency -> pipelines freely.
__global__ void place_kernel(const int* __restrict__ rows, const int* __restrict__ cols,
                             const float* __restrict__ vals,
                             const unsigned short* __restrict__ rank,
                             const int* __restrict__ offsets, int2* __restrict__ edges) {
  int i = blockIdx.x * 256 + threadIdx.x;
  if (i >= ESTRIDE) return;  // each i owns exactly edges {i, i+E/4, i+2E/4, i+3E/4}
#pragma unroll
  for (int j = 0; j < 4; j++) {
    int e = i + j * ESTRIDE;
    int r = rows[e];
    int p = offsets[r] + (int)rank[e];
    int2 rec;
    rec.x = cols[e];
    rec.y = __float_as_int(vals[e]);
    edges[p] = rec;
  }
}

// Fused: blocks [0, GEMM_BLOCKS) compute H = bf16(X @ W^T + b); blocks
// [GEMM_BLOCKS, +RANK_BLOCKS) run histogram+rank atomics.
//
// gemm (m97-style DMA pipeline): 512 threads = 8 waves. Block tile 64 rows x 128
// cols. Wave w: rows (w&3)*16, col-half (w>>2)*64 (4 n-tiles), bfrag[4][8]
// pre-loaded to registers at block start (128 VGPR; no global loads inside the
// K-loop). X is staged fp32 into LDS via __builtin_amdgcn_global_load_lds
// (width 16, one instruction per wave per tile: wave w stakes rows w*8..w*8+7),
// double-buffered 2x8KB. The compiler cannot sink these DMAs (R6 lesson: it
// re-sank every register hoist; VGPR stayed 68 and we ran at 830 GB/s).
// Swizzle: LDS[row][c] = X[row][c ^ (row&7)] (16B chunks) so the two
// ds_read_b128 per lane spread over all 32 banks (8 touches/bank = minimum).
// Barrier per K-step: its vmcnt(0) drain is the DMA completion handshake.
// D: col = lane&15, row = quad*4 + reg  [m89 layout]
__global__ __launch_bounds__(512) void gemm_rank_kernel(
    const float* __restrict__ X, const short* __restrict__ Wb,
    const float* __restrict__ bias, unsigned short* __restrict__ H,
    const int* __restrict__ rows, int* __restrict__ counts,
    unsigned short* __restrict__ rank) {
  __shared__ float xs[2][2048];  // 2 x (64 rows x 32 floats), 16 KB

  if (blockIdx.x >= GEMM_BLOCKS) {
    // ---- rank path: 4 independent atomic chains per thread ----
    int i = (blockIdx.x - GEMM_BLOCKS) * 512 + threadIdx.x;
    if (i >= ESTRIDE) return;
#pragma unroll
    for (int j = 0; j < 4; j++) {
      int e = i + j * ESTRIDE;
      int r = rows[e];
      rank[e] = (unsigned short)atomicAdd(&counts[r], 1);
    }
    return;
  }

  // ---- gemm path ----
  const int tid = threadIdx.x;
  const int w = tid >> 6;    // wave 0..7
  const int lane = tid & 63;
  const int l16 = lane & 15;
  const int quad = lane >> 4;
  const int wr = w & 3;      // row-group
  const int wc = w >> 2;     // col-half
  const int rowBase = blockIdx.x * 64;

  // B fragments to registers: bfrag[t][k] = Wb[wc*64 + t*16 + l16][k*32 + quad*8 ..+7]
  short8 bfrag[4][8];
#pragma unroll
  for (int t = 0; t < 4; t++) {
    const short* bp = Wb + (size_t)(wc * 64 + t * 16 + l16) * KDIM + quad * 8;
#pragma unroll
    for (int k = 0; k < 8; k++) bfrag[t][k] = *(const short8*)(bp + k * 32);
  }

  // DMA source: lane stakes 16 B of row rowBase + w*8 + (lane>>3), swizzled chunk
  const int rl = lane >> 3;  // 0..7 row-local
  const int ch = lane & 7;   // chunk slot in LDS
  int grow = rowBase + w * 8 + rl;
  if (grow >= NNODES) grow = NNODES - 1;  // clamp; garbage rows masked at store
  const float* gsrc = X + (size_t)grow * KDIM + ((ch ^ rl) << 2);

  floatx4 acc[4];
#pragma unroll
  for (int t = 0; t < 4; t++) acc[t] = (floatx4){0.f, 0.f, 0.f, 0.f};

  // prologue: DMA tile 0
  __builtin_amdgcn_global_load_lds((gas_u32*)gsrc, (lds_u32*)&xs[0][w * 256], 16, 0, 0);
  __syncthreads();  // vmcnt(0) drain -> tile 0 resident

#pragma unroll
  for (int k = 0; k < 8; k++) {
    if (k < 7) {  // DMA tile k+1 into the other buffer; overlaps this step's compute
      __builtin_amdgcn_global_load_lds((gas_u32*)(gsrc + (k + 1) * 32),
                                       (lds_u32*)&xs[(k + 1) & 1][w * 256], 16, 0, 0);
    }
    const float* base = &xs[k & 1][(wr * 16 + l16) * 32];
    const float4 c0 = *(const float4*)(base + (((2 * quad) ^ (l16 & 7)) << 2));
    const float4 c1 = *(const float4*)(base + (((2 * quad + 1) ^ (l16 & 7)) << 2));
    short8 a;
    a[0] = f2bf(c0.x); a[1] = f2bf(c0.y); a[2] = f2bf(c0.z); a[3] = f2bf(c0.w);
    a[4] = f2bf(c1.x); a[5] = f2bf(c1.y); a[6] = f2bf(c1.z); a[7] = f2bf(c1.w);
#pragma unroll
    for (int t = 0; t < 4; t++)
      acc[t] = __builtin_amdgcn_mfma_f32_16x16x32_bf16(a, bfrag[t][k], acc[t], 0, 0, 0);
    __syncthreads();  // (a) all waves done reading buf k&1; (b) vmcnt drain completes tile k+1
  }

#pragma unroll
  for (int t = 0; t < 4; t++) {
    const int col = wc * 64 + t * 16 + l16;
    const float bv = bias[col];
#pragma unroll
    for (int r = 0; r < 4; r++) {
      const int row = rowBase + wr * 16 + quad * 4 + r;
      if (row < NNODES) H[(size_t)row * ODIM + col] = (unsigned short)f2bf(acc[t][r] + bv);
    }
  }
}

// Two rows per wave = 2 independent gather chains (8 gathers in flight), CSR with
// 4-padded segments (pad records are {col 0, val 0} from the memset -> no masking;
// the i<len guards are wave-uniform branches, both rows belong to the whole wave).
// Lane owns channels {2*lane, 2*lane+1}: one uint = 2 bf16, 256 B/edge coalesced.
__global__ __launch_bounds__(256) void spmm_kernel(const int* __restrict__ offsets,
                                                   const int2* __restrict__ edges,
                                                   const unsigned* __restrict__ H2,
                                                   float* __restrict__ out) {
  const int lane = threadIdx.x & 63;
  const int wid = blockIdx.x * 4 + (threadIdx.x >> 6);
  const int r0 = wid * 2;
  const int r1 = r0 + 1;  // NNODES even -> r1 valid whenever r0 is
  if (r0 >= NNODES) return;
  const int s0 = offsets[r0];
  const int s1 = offsets[r1];
  const int e1 = offsets[r1 + 1];
  const int len0 = s1 - s0;  // padded, multiple of 4
  const int len1 = e1 - s1;
  const int2* p0 = edges + s0;
  const int2* p1 = edges + s1;
  float ax0 = 0.f, ay0 = 0.f, ax1 = 0.f, ay1 = 0.f;
  const int it = len0 > len1 ? len0 : len1;
#define EDGE_ACC(px, py, ax, ay)                              \
  {                                                           \
    const unsigned h = H2[(size_t)(px) * 64 + lane];          \
    const float v = __int_as_float(py);                       \
    ax += v * __uint_as_float(h << 16);                       \
    ay += v * __uint_as_float(h & 0xffff0000u);               \
  }
  for (int i = 0; i < it; i += 4) {
    if (i < len0) {
      const int4 a01 = *(const int4*)(p0 + i);
      const int4 a23 = *(const int4*)(p0 + i + 2);
      EDGE_ACC(a01.x, a01.y, ax0, ay0)
      EDGE_ACC(a01.z, a01.w, ax0, ay0)
      EDGE_ACC(a23.x, a23.y, ax0, ay0)
      EDGE_ACC(a23.z, a23.w, ax0, ay0)
    }
    if (i < len1) {
      const int4 b01 = *(const int4*)(p1 + i);
      const int4 b23 = *(const int4*)(p1 + i + 2);
      EDGE_ACC(b01.x, b01.y, ax1, ay1)
      EDGE_ACC(b01.z, b01.w, ax1, ay1)
      EDGE_ACC(b23.x, b23.y, ax1, ay1)
      EDGE_ACC(b23.z, b23.w, ax1, ay1)
    }
  }
#undef EDGE_ACC
  float2 o0, o1;
  o0.x = ax0; o0.y = ay0;
  o1.x = ax1; o1.y = ay1;
  ((float2*)out)[(size_t)r0 * 64 + lane] = o0;
  ((float2*)out)[(size_t)r1 * 64 + lane] = o1;
}

extern "C" void kernel_launch(void* const* d_in, const int* in_sizes, int n_in,
                              void* d_out, int out_size, void* d_ws, size_t ws_size,
                              hipStream_t stream) {
  const float* X = (const float*)d_in[0];
  const int* erow = (const int*)d_in[1];
  const int* ecol = (const int*)d_in[2];
  const float* eval = (const float*)d_in[3];
  const float* W = (const float*)d_in[4];
  const float* bias = (const float*)d_in[5];
  float* out = (float*)d_out;

  char* ws = (char*)d_ws;
  size_t off = 0;
  auto alloc = [&](size_t bytes) -> char* {
    char* p = ws + off;
    off += (bytes + 255) & ~(size_t)255;
    return p;
  };
  // total ~45.4 MB — the R4 footprint known to fit ws_size
  unsigned short* Hb = (unsigned short*)alloc((size_t)NNODES * ODIM * 2);  // 25.6 MB
  short* Wb = (short*)alloc((size_t)ODIM * KDIM * 2);                      // 64 KB
  int* counts = (int*)alloc((size_t)NNODES * 4);
  int* chunkExcl = (int*)alloc((size_t)NNODES * 4);
  int* offsets = (int*)alloc((size_t)(NNODES + 1) * 4);
  int* blockSums = (int*)alloc((size_t)NB_SCAN * 4);
  int* blockBase = (int*)alloc((size_t)NB_SCAN * 4);
  unsigned short* rank = (unsigned short*)alloc((size_t)NEDGES * 2);  // 3.2 MB
  int2* edges = (int2*)alloc((size_t)EDGE_CAP * 8);  // 15.2 MB, padded CSR records

  hipMemsetAsync(counts, 0, (size_t)NNODES * 4, stream);
  hipMemsetAsync(edges, 0, (size_t)EDGE_CAP * 8, stream);  // pad records = {col 0, val 0}
  conv_w_kernel<<<(ODIM * KDIM + 255) / 256, 256, 0, stream>>>(W, Wb);
  gemm_rank_kernel<<<GEMM_BLOCKS + RANK_BLOCKS, 512, 0, stream>>>(X, Wb, bias, Hb,
                                                                  erow, counts, rank);
  scan1_kernel<<<NB_SCAN, 256, 0, stream>>>(counts, chunkExcl, blockSums);
  scan2_kernel<<<1, 128, 0, stream>>>(blockSums, blockBase, offsets);
  scan3_kernel<<<(NNODES + 255) / 256, 256, 0, stream>>>(chunkExcl, blockBase, offsets);
  place_kernel<<<(ESTRIDE + 255) / 256, 256, 0, stream>>>(erow, ecol, eval, rank, offsets, edges);
  spmm_kernel<<<(NNODES / 2 + 3) / 4, 256, 0, stream>>>(offsets, edges, (const unsigned*)Hb, out);
}